// Round 11
// baseline (75.374 us; speedup 1.0000x reference)
//
#include <hip/hip_runtime.h>

// Grouped VQ: bf16-MFMA screen + exact-fp32 rescue, v11.
// vs v10 (64us): (1) 64 tokens/wave (4 subtiles) -> per-ct fixed costs
// amortize 2x, waves halve, 4 independent chains/wave (ILP); grid 512,
// lb(256,2) VGPR cap 256 (~170 working set, no spill); (2) exact top-2 in
// 3 ops/dist via v_med3_u32: best'=umin(bo,k), sec'=med3(bo,sec,k).
// LDS double-buffer b-path identical to v10 (proven). Numerics class
// unchanged: d = cn64[code] + <x,-2c>_bf16 (C-folded MFMA), 22-bit key |
// 10-bit code, EPS=0.10, exact-fp32 rescue in reference order.

#define NTOK   16384
#define DMODEL 512
#define NGRP   8
#define DG     64
#define NCODE  1024
#define EPS    0.10f

#define STG_ELEM 8192        // 8 ct-tiles * 1024 bf16 = 16 KB

typedef __attribute__((ext_vector_type(8))) __bf16 bf16x8;
typedef __attribute__((ext_vector_type(4))) float  f32x4;

__device__ __forceinline__ unsigned umin_(unsigned a, unsigned b){ return a<b?a:b; }

// exact running top-2 update: returns via refs. new_best = min(bo,k),
// new_sec = median{bo, sec, k}  (bo = old best; bo <= sec invariant).
__device__ __forceinline__ void top2_(unsigned& best, unsigned& sec, unsigned key)
{
    unsigned bo = best;
    best = umin_(bo, key);
    unsigned ns;
    asm("v_med3_u32 %0, %1, %2, %3" : "=v"(ns) : "v"(bo), "v"(sec), "v"(key));
    sec = ns;
}

// ---------------- prep: pack codebook into B-fragment layout (bf16) --------
// Stores -2*c. ws_b element index = (((g*64 + ct)*2 + s)*64 + lane)*8 + j
//   holds -2*cb[g][ct*16 + (lane&15)][s*32 + (lane>>4)*8 + j] as bf16.
__global__ __launch_bounds__(256) void prep_frags(
    const float* __restrict__ cb, __bf16* __restrict__ wb)
{
    int tid  = blockIdx.x * 256 + threadIdx.x;      // 0..65535
    int lane = tid & 63;
    int s    = (tid >> 6) & 1;
    int ct   = (tid >> 7) & 63;
    int g    = tid >> 13;
    int code = ct * 16 + (lane & 15);
    int k0   = s * 32 + (lane >> 4) * 8;
    const float* src = cb + ((size_t)g * NCODE + code) * DG + k0;
    bf16x8 v;
    #pragma unroll
    for (int j = 0; j < 8; ++j) v[j] = (__bf16)(-2.0f * src[j]);
    *reinterpret_cast<bf16x8*>(wb + (size_t)tid * 8) = v;
}

__global__ __launch_bounds__(256) void prep_cnorm(
    const float* __restrict__ cb, float* __restrict__ wcn)
{
    int i = blockIdx.x * 256 + threadIdx.x;         // 0..8191 (g*1024+code)
    const float4* c4 = reinterpret_cast<const float4*>(cb + (size_t)i * DG);
    float s = 0.0f;
    #pragma unroll
    for (int j = 0; j < 16; ++j) {
        float4 v = c4[j];
        s = fmaf(v.x, v.x, s); s = fmaf(v.y, v.y, s);
        s = fmaf(v.z, v.z, s); s = fmaf(v.w, v.w, s);
    }
    wcn[i] = s;
}

__device__ __forceinline__ float dotc(const float* __restrict__ a,
                                      const float* __restrict__ b)
{
    const float4* a4 = reinterpret_cast<const float4*>(a);
    const float4* b4 = reinterpret_cast<const float4*>(b);
    float s = 0.0f;
    #pragma unroll 4
    for (int j = 0; j < 16; ++j) {
        float4 u = a4[j], v = b4[j];
        s = fmaf(u.x, v.x, s); s = fmaf(u.y, v.y, s);
        s = fmaf(u.z, v.z, s); s = fmaf(u.w, v.w, s);
    }
    return s;
}

__device__ __forceinline__ bf16x8 cvt8(const float* __restrict__ p)
{
    float4 u = *reinterpret_cast<const float4*>(p);
    float4 v = *reinterpret_cast<const float4*>(p + 4);
    bf16x8 r;
    r[0]=(__bf16)u.x; r[1]=(__bf16)u.y; r[2]=(__bf16)u.z; r[3]=(__bf16)u.w;
    r[4]=(__bf16)v.x; r[5]=(__bf16)v.y; r[6]=(__bf16)v.z; r[7]=(__bf16)v.w;
    return r;
}

// ---------------- main: screen + rescue ------------------------------------
// Block = 256 threads (4 waves), each wave 64 tokens (4 subtiles); block =
// 256 tokens x 1 group. Grid = 64 tiles * 8 groups = 512 blocks.
__global__ __launch_bounds__(256, 2) void vq_mfma_kernel(
    const float*  __restrict__ x,
    const float*  __restrict__ cb,
    const __bf16* __restrict__ wb,
    const float*  __restrict__ wcn,
    float* __restrict__ out)
{
    __shared__ __bf16 bbufA[STG_ELEM];   // 16 KB
    __shared__ __bf16 bbufB[STG_ELEM];   // 16 KB
    __shared__ float  cn64[NCODE];       //  4 KB

    const int tid  = threadIdx.x;
    const int lane = tid & 63;
    const int wv   = tid >> 6;
    const int g    = blockIdx.x & 7;
    const int tile = blockIdx.x >> 3;

    const __bf16* wbg = wb + (size_t)g * (NCODE * DG);
    const int sbase = wv * 2048 + lane * 8;   // element offset within a stage

    bf16x8 r0, r1, r2, r3;   // in-flight stage registers

#define LOADSTG(st) do {                                                  \
    const __bf16* sp_ = wbg + (size_t)(st) * STG_ELEM + sbase;            \
    r0 = *reinterpret_cast<const bf16x8*>(sp_);                           \
    r1 = *reinterpret_cast<const bf16x8*>(sp_ + 512);                     \
    r2 = *reinterpret_cast<const bf16x8*>(sp_ + 1024);                    \
    r3 = *reinterpret_cast<const bf16x8*>(sp_ + 1536);                    \
} while (0)

#define WRITESTG(bufp) do {                                               \
    __bf16* dp_ = (bufp) + sbase;                                         \
    *reinterpret_cast<bf16x8*>(dp_)        = r0;                          \
    *reinterpret_cast<bf16x8*>(dp_ + 512)  = r1;                          \
    *reinterpret_cast<bf16x8*>(dp_ + 1024) = r2;                          \
    *reinterpret_cast<bf16x8*>(dp_ + 1536) = r3;                          \
} while (0)

#define COMPUTESTG(bufp, st) do {                                         \
    _Pragma("unroll 2")                                                   \
    for (int ctl_ = 0; ctl_ < 8; ++ctl_) {                                \
        bf16x8 b0_ = *reinterpret_cast<const bf16x8*>((bufp) + ctl_ * 1024 + lane * 8);        \
        bf16x8 b1_ = *reinterpret_cast<const bf16x8*>((bufp) + ctl_ * 1024 + 512 + lane * 8);  \
        const int code_ = (st) * 128 + ctl_ * 16 + row;                   \
        const float cnv_ = cn64[code_];                                   \
        const f32x4 ci_ = {cnv_, cnv_, cnv_, cnv_};                       \
        _Pragma("unroll")                                                 \
        for (int s_ = 0; s_ < 4; ++s_) {                                  \
            f32x4 z_ = __builtin_amdgcn_mfma_f32_16x16x32_bf16(aA[s_], b0_, ci_, 0, 0, 0); \
            f32x4 d_ = __builtin_amdgcn_mfma_f32_16x16x32_bf16(aB[s_], b1_, z_, 0, 0, 0);  \
            _Pragma("unroll")                                             \
            for (int r_ = 0; r_ < 4; ++r_) {                              \
                unsigned key_ = (__float_as_uint(d_[r_]) & 0xFFFFFC00u) | (unsigned)code_; \
                top2_(best[s_][r_], sec[s_][r_], key_);                   \
            }                                                             \
        }                                                                 \
    }                                                                     \
} while (0)

    // ---- prologue: stage 0 -> regs; cn64; A-fragments; write stage 0 ----
    LOADSTG(0);

    {   // cn+64 (screen bias; rescue uses true wcn)
        float4 v = reinterpret_cast<const float4*>(wcn + g * NCODE)[tid];
        v.x += 64.0f; v.y += 64.0f; v.z += 64.0f; v.w += 64.0f;
        reinterpret_cast<float4*>(cn64)[tid] = v;
    }

    const int row  = lane & 15;
    const int q    = lane >> 4;
    const int k0   = q * 8;
    const int tok0 = tile * 256 + wv * 64;

    bf16x8 aA[4], aB[4];
    #pragma unroll
    for (int s = 0; s < 4; ++s) {
        const float* xr = x + (size_t)(tok0 + s * 16 + row) * DMODEL + g * DG;
        aA[s] = cvt8(xr + k0);
        aB[s] = cvt8(xr + 32 + k0);
    }

    unsigned best[4][4], sec[4][4];
    #pragma unroll
    for (int s = 0; s < 4; ++s)
        #pragma unroll
        for (int r = 0; r < 4; ++r) { best[s][r] = 0xFFFFFFFFu; sec[s][r] = 0xFFFFFFFFu; }

    WRITESTG(bbufA);     // vmcnt wait lands here; ds_write stage 0
    __syncthreads();     // bufA + cn64 visible to all waves

    // ---- 8 stages, double-buffered, one barrier per stage ----
    for (int stp = 0; stp < 4; ++stp) {
        const int stE = stp * 2, stO = stp * 2 + 1;

        LOADSTG(stO);                 // in flight under even compute
        COMPUTESTG(bbufA, stE);
        WRITESTG(bbufB);              // prev bufB readers done (last barrier)
        __syncthreads();              // bufB ready

        if (stp < 3) {
            LOADSTG(stE + 2);         // in flight under odd compute
            COMPUTESTG(bbufB, stO);
            WRITESTG(bbufA);          // prev bufA readers done (last barrier)
            __syncthreads();          // bufA ready
        } else {
            COMPUTESTG(bbufB, stO);   // final stage: no prefetch
        }
    }

    // min-reduce packed keys across each 16-lane col group (q-group)
    unsigned mk[4][4];
    #pragma unroll
    for (int s = 0; s < 4; ++s)
        #pragma unroll
        for (int r = 0; r < 4; ++r) mk[s][r] = best[s][r];
    #pragma unroll
    for (int mask = 1; mask < 16; mask <<= 1) {
        #pragma unroll
        for (int s = 0; s < 4; ++s)
            #pragma unroll
            for (int r = 0; r < 4; ++r) {
                unsigned o = (unsigned)__shfl_xor((int)mk[s][r], mask, 64);
                mk[s][r] = umin_(mk[s][r], o);
            }
    }

    const float* cbg  = cb  + (size_t)g * NCODE * DG;
    const float* wcng = wcn + (size_t)g * NCODE;

    #pragma unroll
    for (int s = 0; s < 4; ++s) {
        #pragma unroll
        for (int r = 0; r < 4; ++r) {
            const unsigned m_ = mk[s][r];
            int sel = (int)(m_ & 0x3FFu);
            const float thr = __uint_as_float(m_ & 0xFFFFFC00u) + EPS;
            const float bd  = __uint_as_float(best[s][r] & 0xFFFFFC00u);
            const float sdd = __uint_as_float(sec[s][r]  & 0xFFFFFC00u);
            const bool oth = (bd <= thr && best[s][r] != m_) || (sdd <= thr);
            const unsigned long long bal = __ballot(oth);
            if (((bal >> (q * 16)) & 0xFFFFULL) != 0ULL) {
                // exact fp32 rescue among tracked candidates
                const int token = tok0 + s * 16 + q * 4 + r;
                const float* xr = x + (size_t)token * DMODEL + g * DG;
                const float xn = dotc(xr, xr);
                float ed = 1e30f; int ei = 0x7FFFFFFF;
                if (bd <= thr) {
                    const int cc = (int)(best[s][r] & 0x3FFu);
                    float dd = (xn + wcng[cc]) - 2.0f * dotc(xr, cbg + (size_t)cc * DG);
                    if (dd < ed || (dd == ed && cc < ei)) { ed = dd; ei = cc; }
                }
                if (sdd <= thr) {
                    const int cc = (int)(sec[s][r] & 0x3FFu);
                    float dd = (xn + wcng[cc]) - 2.0f * dotc(xr, cbg + (size_t)cc * DG);
                    if (dd < ed || (dd == ed && cc < ei)) { ed = dd; ei = cc; }
                }
                #pragma unroll
                for (int mask = 1; mask < 16; mask <<= 1) {
                    float pd = __shfl_xor(ed, mask, 64);
                    int   pi = __shfl_xor(ei, mask, 64);
                    if (pd < ed || (pd == ed && pi < ei)) { ed = pd; ei = pi; }
                }
                sel = ei;
            }
            // write the selected code row (16 lanes x float4 = 64 floats)
            const int token = tok0 + s * 16 + q * 4 + r;
            const float4 src = reinterpret_cast<const float4*>(cbg + (size_t)sel * DG)[row];
            reinterpret_cast<float4*>(out + (size_t)token * DMODEL + g * DG)[row] = src;
        }
    }
#undef LOADSTG
#undef WRITESTG
#undef COMPUTESTG
}

// ---------------- fp32 fallback (ws too small) -----------------------------
__global__ __launch_bounds__(512, 4) void vq_fp32_kernel(
    const float* __restrict__ x,
    const float* __restrict__ cb,
    float* __restrict__ out)
{
    __shared__ float cnl[NGRP][NCODE];
    const int tid  = threadIdx.x;
    const int lane = tid & 63;
    const int wave = tid >> 6;
    const int g    = __builtin_amdgcn_readfirstlane(wave);
    const int token = blockIdx.x * 64 + lane;
    const float* __restrict__ cbg = cb + (size_t)g * NCODE * DG;

    for (int kk = lane; kk < NCODE; kk += 64) {
        const float4* c4 = reinterpret_cast<const float4*>(cbg + kk * DG);
        float s = 0.0f;
        #pragma unroll
        for (int j = 0; j < 16; ++j) {
            float4 v = c4[j];
            s = fmaf(v.x, v.x, s); s = fmaf(v.y, v.y, s);
            s = fmaf(v.z, v.z, s); s = fmaf(v.w, v.w, s);
        }
        cnl[g][kk] = s;
    }
    __syncthreads();

    const float* xr = x + (size_t)token * DMODEL + g * DG;
    float xn = dotc(xr, xr);
    float bestv = 3.4e38f; int bidx = 0;
    for (int k = 0; k < NCODE; ++k) {
        float dist = (xn + cnl[g][k]) - 2.0f * dotc(xr, cbg + (size_t)k * DG);
        if (dist < bestv) { bestv = dist; bidx = k; }
    }
    const float4* q4 = reinterpret_cast<const float4*>(cbg + (size_t)bidx * DG);
    float4* o4 = reinterpret_cast<float4*>(out + (size_t)token * DMODEL + g * DG);
    #pragma unroll
    for (int j = 0; j < 16; ++j) o4[j] = q4[j];
}

extern "C" void kernel_launch(void* const* d_in, const int* in_sizes, int n_in,
                              void* d_out, int out_size, void* d_ws, size_t ws_size,
                              hipStream_t stream) {
    const float* x  = (const float*)d_in[0];
    const float* cb = (const float*)d_in[1];
    float* out = (float*)d_out;

    const size_t wb_bytes = (size_t)NGRP * NCODE * DG * sizeof(__bf16); // 1 MB
    const size_t cn_bytes = (size_t)NGRP * NCODE * sizeof(float);       // 32 KB
    if (ws_size < wb_bytes + cn_bytes) {
        vq_fp32_kernel<<<256, 512, 0, stream>>>(x, cb, out);
        return;
    }
    __bf16* wb  = (__bf16*)d_ws;
    float*  wcn = (float*)((char*)d_ws + wb_bytes);

    prep_frags<<<256, 256, 0, stream>>>(cb, wb);
    prep_cnorm<<<32, 256, 0, stream>>>(cb, wcn);
    vq_mfma_kernel<<<512, 256, 0, stream>>>(x, cb, wb, wcn, out);
}

// Round 12
// 63.093 us; speedup vs baseline: 1.1947x; 1.1947x over previous
//
#include <hip/hip_runtime.h>

// Grouped VQ: bf16-MFMA screen + exact-fp32 rescue, v12.
// = v10 (proven 64us) + two changes:
// (1) VGPR pinning: empty asm "+v" constraints on A-fragments (once) and on
//     each MFMA result d_ -> forces VGPR class, kills v_accvgpr_read/write
//     marshalling (v10/v11 counters: VGPR_Count 56/84 with hidden AGPR
//     allocation -> ~2.5x VALU inflation + occupancy loss).
// (2) exact top-2 in 3 ops/dist via v_med3_u32 (refcheck'd in v11):
//     best' = umin(bo,k); sec' = med3(bo,sec,k).
// Numerics unchanged (proven): d = cn64[code] + <x,-2c>_bf16 (C-folded
// MFMA), 22-bit key | 10-bit code, EPS=0.10, exact-fp32 rescue, ref order.

#define NTOK   16384
#define DMODEL 512
#define NGRP   8
#define DG     64
#define NCODE  1024
#define EPS    0.10f

#define STG_ELEM 8192        // 8 ct-tiles * 1024 bf16 = 16 KB

typedef __attribute__((ext_vector_type(8))) __bf16 bf16x8;
typedef __attribute__((ext_vector_type(4))) float  f32x4;

__device__ __forceinline__ unsigned umin_(unsigned a, unsigned b){ return a<b?a:b; }

// exact running top-2: best' = min(bo,k), sec' = median{bo, sec, k}.
__device__ __forceinline__ void top2_(unsigned& best, unsigned& sec, unsigned key)
{
    unsigned bo = best;
    best = umin_(bo, key);
    unsigned ns;
    asm("v_med3_u32 %0, %1, %2, %3" : "=v"(ns) : "v"(bo), "v"(sec), "v"(key));
    sec = ns;
}

// ---------------- prep: pack codebook into B-fragment layout (bf16) --------
// Stores -2*c. ws_b element index = (((g*64 + ct)*2 + s)*64 + lane)*8 + j
//   holds -2*cb[g][ct*16 + (lane&15)][s*32 + (lane>>4)*8 + j] as bf16.
__global__ __launch_bounds__(256) void prep_frags(
    const float* __restrict__ cb, __bf16* __restrict__ wb)
{
    int tid  = blockIdx.x * 256 + threadIdx.x;      // 0..65535
    int lane = tid & 63;
    int s    = (tid >> 6) & 1;
    int ct   = (tid >> 7) & 63;
    int g    = tid >> 13;
    int code = ct * 16 + (lane & 15);
    int k0   = s * 32 + (lane >> 4) * 8;
    const float* src = cb + ((size_t)g * NCODE + code) * DG + k0;
    bf16x8 v;
    #pragma unroll
    for (int j = 0; j < 8; ++j) v[j] = (__bf16)(-2.0f * src[j]);
    *reinterpret_cast<bf16x8*>(wb + (size_t)tid * 8) = v;
}

__global__ __launch_bounds__(256) void prep_cnorm(
    const float* __restrict__ cb, float* __restrict__ wcn)
{
    int i = blockIdx.x * 256 + threadIdx.x;         // 0..8191 (g*1024+code)
    const float4* c4 = reinterpret_cast<const float4*>(cb + (size_t)i * DG);
    float s = 0.0f;
    #pragma unroll
    for (int j = 0; j < 16; ++j) {
        float4 v = c4[j];
        s = fmaf(v.x, v.x, s); s = fmaf(v.y, v.y, s);
        s = fmaf(v.z, v.z, s); s = fmaf(v.w, v.w, s);
    }
    wcn[i] = s;
}

__device__ __forceinline__ float dotc(const float* __restrict__ a,
                                      const float* __restrict__ b)
{
    const float4* a4 = reinterpret_cast<const float4*>(a);
    const float4* b4 = reinterpret_cast<const float4*>(b);
    float s = 0.0f;
    #pragma unroll 4
    for (int j = 0; j < 16; ++j) {
        float4 u = a4[j], v = b4[j];
        s = fmaf(u.x, v.x, s); s = fmaf(u.y, v.y, s);
        s = fmaf(u.z, v.z, s); s = fmaf(u.w, v.w, s);
    }
    return s;
}

__device__ __forceinline__ bf16x8 cvt8(const float* __restrict__ p)
{
    float4 u = *reinterpret_cast<const float4*>(p);
    float4 v = *reinterpret_cast<const float4*>(p + 4);
    bf16x8 r;
    r[0]=(__bf16)u.x; r[1]=(__bf16)u.y; r[2]=(__bf16)u.z; r[3]=(__bf16)u.w;
    r[4]=(__bf16)v.x; r[5]=(__bf16)v.y; r[6]=(__bf16)v.z; r[7]=(__bf16)v.w;
    return r;
}

// ---------------- main: screen + rescue ------------------------------------
// Block = 256 threads (4 waves), each wave 32 tokens; block = 128 tokens x
// 1 group. Grid = 128 tiles * 8 groups = 1024 blocks.
__global__ __launch_bounds__(256, 4) void vq_mfma_kernel(
    const float*  __restrict__ x,
    const float*  __restrict__ cb,
    const __bf16* __restrict__ wb,
    const float*  __restrict__ wcn,
    float* __restrict__ out)
{
    __shared__ __bf16 bbufA[STG_ELEM];   // 16 KB
    __shared__ __bf16 bbufB[STG_ELEM];   // 16 KB
    __shared__ float  cn64[NCODE];       //  4 KB

    const int tid  = threadIdx.x;
    const int lane = tid & 63;
    const int wv   = tid >> 6;
    const int g    = blockIdx.x & 7;
    const int tile = blockIdx.x >> 3;

    const __bf16* wbg = wb + (size_t)g * (NCODE * DG);
    const int sbase = wv * 2048 + lane * 8;   // element offset within a stage

    bf16x8 r0, r1, r2, r3;   // in-flight stage registers

#define LOADSTG(st) do {                                                  \
    const __bf16* sp_ = wbg + (size_t)(st) * STG_ELEM + sbase;            \
    r0 = *reinterpret_cast<const bf16x8*>(sp_);                           \
    r1 = *reinterpret_cast<const bf16x8*>(sp_ + 512);                     \
    r2 = *reinterpret_cast<const bf16x8*>(sp_ + 1024);                    \
    r3 = *reinterpret_cast<const bf16x8*>(sp_ + 1536);                    \
} while (0)

#define WRITESTG(bufp) do {                                               \
    __bf16* dp_ = (bufp) + sbase;                                         \
    *reinterpret_cast<bf16x8*>(dp_)        = r0;                          \
    *reinterpret_cast<bf16x8*>(dp_ + 512)  = r1;                          \
    *reinterpret_cast<bf16x8*>(dp_ + 1024) = r2;                          \
    *reinterpret_cast<bf16x8*>(dp_ + 1536) = r3;                          \
} while (0)

#define COMPUTESTG(bufp, st) do {                                         \
    _Pragma("unroll 2")                                                   \
    for (int ctl_ = 0; ctl_ < 8; ++ctl_) {                                \
        bf16x8 b0_ = *reinterpret_cast<const bf16x8*>((bufp) + ctl_ * 1024 + lane * 8);        \
        bf16x8 b1_ = *reinterpret_cast<const bf16x8*>((bufp) + ctl_ * 1024 + 512 + lane * 8);  \
        const int code_ = (st) * 128 + ctl_ * 16 + row;                   \
        const float cnv_ = cn64[code_];                                   \
        const f32x4 ci_ = {cnv_, cnv_, cnv_, cnv_};                       \
        _Pragma("unroll")                                                 \
        for (int s_ = 0; s_ < 2; ++s_) {                                  \
            f32x4 z_ = __builtin_amdgcn_mfma_f32_16x16x32_bf16(aA[s_], b0_, ci_, 0, 0, 0); \
            f32x4 d_ = __builtin_amdgcn_mfma_f32_16x16x32_bf16(aB[s_], b1_, z_, 0, 0, 0);  \
            asm("" : "+v"(d_));   /* pin MFMA result to VGPR class */     \
            _Pragma("unroll")                                             \
            for (int r_ = 0; r_ < 4; ++r_) {                              \
                unsigned key_ = (__float_as_uint(d_[r_]) & 0xFFFFFC00u) | (unsigned)code_; \
                top2_(best[s_][r_], sec[s_][r_], key_);                   \
            }                                                             \
        }                                                                 \
    }                                                                     \
} while (0)

    // ---- prologue: stage 0 -> regs; cn64; A-fragments; write stage 0 ----
    LOADSTG(0);

    {   // cn+64 (screen bias; rescue uses true wcn)
        float4 v = reinterpret_cast<const float4*>(wcn + g * NCODE)[tid];
        v.x += 64.0f; v.y += 64.0f; v.z += 64.0f; v.w += 64.0f;
        reinterpret_cast<float4*>(cn64)[tid] = v;
    }

    const int row  = lane & 15;
    const int q    = lane >> 4;
    const int k0   = q * 8;
    const int tok0 = tile * 128 + wv * 32;

    bf16x8 aA[2], aB[2];
    #pragma unroll
    for (int s = 0; s < 2; ++s) {
        const float* xr = x + (size_t)(tok0 + s * 16 + row) * DMODEL + g * DG;
        aA[s] = cvt8(xr + k0);
        aB[s] = cvt8(xr + 32 + k0);
        asm("" : "+v"(aA[s]));   // pin A-fragments to VGPR class (one-time)
        asm("" : "+v"(aB[s]));
    }

    unsigned best[2][4], sec[2][4];
    #pragma unroll
    for (int s = 0; s < 2; ++s)
        #pragma unroll
        for (int r = 0; r < 4; ++r) { best[s][r] = 0xFFFFFFFFu; sec[s][r] = 0xFFFFFFFFu; }

    WRITESTG(bbufA);     // vmcnt wait lands here; ds_write stage 0
    __syncthreads();     // bufA + cn64 visible to all waves

    // ---- 8 stages, double-buffered, one barrier per stage ----
    for (int stp = 0; stp < 4; ++stp) {
        const int stE = stp * 2, stO = stp * 2 + 1;

        LOADSTG(stO);                 // in flight under even compute
        COMPUTESTG(bbufA, stE);
        WRITESTG(bbufB);              // prev bufB readers done (last barrier)
        __syncthreads();              // bufB ready

        if (stp < 3) {
            LOADSTG(stE + 2);         // in flight under odd compute
            COMPUTESTG(bbufB, stO);
            WRITESTG(bbufA);          // prev bufA readers done (last barrier)
            __syncthreads();          // bufA ready
        } else {
            COMPUTESTG(bbufB, stO);   // final stage: no prefetch
        }
    }

    // min-reduce packed keys across each 16-lane col group (q-group)
    unsigned mk[2][4];
    #pragma unroll
    for (int s = 0; s < 2; ++s)
        #pragma unroll
        for (int r = 0; r < 4; ++r) mk[s][r] = best[s][r];
    #pragma unroll
    for (int mask = 1; mask < 16; mask <<= 1) {
        #pragma unroll
        for (int s = 0; s < 2; ++s)
            #pragma unroll
            for (int r = 0; r < 4; ++r) {
                unsigned o = (unsigned)__shfl_xor((int)mk[s][r], mask, 64);
                mk[s][r] = umin_(mk[s][r], o);
            }
    }

    const float* cbg  = cb  + (size_t)g * NCODE * DG;
    const float* wcng = wcn + (size_t)g * NCODE;

    #pragma unroll
    for (int s = 0; s < 2; ++s) {
        #pragma unroll
        for (int r = 0; r < 4; ++r) {
            const unsigned m_ = mk[s][r];
            int sel = (int)(m_ & 0x3FFu);
            const float thr = __uint_as_float(m_ & 0xFFFFFC00u) + EPS;
            const float bd  = __uint_as_float(best[s][r] & 0xFFFFFC00u);
            const float sdd = __uint_as_float(sec[s][r]  & 0xFFFFFC00u);
            const bool oth = (bd <= thr && best[s][r] != m_) || (sdd <= thr);
            const unsigned long long bal = __ballot(oth);
            if (((bal >> (q * 16)) & 0xFFFFULL) != 0ULL) {
                // exact fp32 rescue among tracked candidates
                const int token = tok0 + s * 16 + q * 4 + r;
                const float* xr = x + (size_t)token * DMODEL + g * DG;
                const float xn = dotc(xr, xr);
                float ed = 1e30f; int ei = 0x7FFFFFFF;
                if (bd <= thr) {
                    const int cc = (int)(best[s][r] & 0x3FFu);
                    float dd = (xn + wcng[cc]) - 2.0f * dotc(xr, cbg + (size_t)cc * DG);
                    if (dd < ed || (dd == ed && cc < ei)) { ed = dd; ei = cc; }
                }
                if (sdd <= thr) {
                    const int cc = (int)(sec[s][r] & 0x3FFu);
                    float dd = (xn + wcng[cc]) - 2.0f * dotc(xr, cbg + (size_t)cc * DG);
                    if (dd < ed || (dd == ed && cc < ei)) { ed = dd; ei = cc; }
                }
                #pragma unroll
                for (int mask = 1; mask < 16; mask <<= 1) {
                    float pd = __shfl_xor(ed, mask, 64);
                    int   pi = __shfl_xor(ei, mask, 64);
                    if (pd < ed || (pd == ed && pi < ei)) { ed = pd; ei = pi; }
                }
                sel = ei;
            }
            // write the selected code row (16 lanes x float4 = 64 floats)
            const int token = tok0 + s * 16 + q * 4 + r;
            const float4 src = reinterpret_cast<const float4*>(cbg + (size_t)sel * DG)[row];
            reinterpret_cast<float4*>(out + (size_t)token * DMODEL + g * DG)[row] = src;
        }
    }
#undef LOADSTG
#undef WRITESTG
#undef COMPUTESTG
}

// ---------------- fp32 fallback (ws too small) -----------------------------
__global__ __launch_bounds__(512, 4) void vq_fp32_kernel(
    const float* __restrict__ x,
    const float* __restrict__ cb,
    float* __restrict__ out)
{
    __shared__ float cnl[NGRP][NCODE];
    const int tid  = threadIdx.x;
    const int lane = tid & 63;
    const int wave = tid >> 6;
    const int g    = __builtin_amdgcn_readfirstlane(wave);
    const int token = blockIdx.x * 64 + lane;
    const float* __restrict__ cbg = cb + (size_t)g * NCODE * DG;

    for (int kk = lane; kk < NCODE; kk += 64) {
        const float4* c4 = reinterpret_cast<const float4*>(cbg + kk * DG);
        float s = 0.0f;
        #pragma unroll
        for (int j = 0; j < 16; ++j) {
            float4 v = c4[j];
            s = fmaf(v.x, v.x, s); s = fmaf(v.y, v.y, s);
            s = fmaf(v.z, v.z, s); s = fmaf(v.w, v.w, s);
        }
        cnl[g][kk] = s;
    }
    __syncthreads();

    const float* xr = x + (size_t)token * DMODEL + g * DG;
    float xn = dotc(xr, xr);
    float bestv = 3.4e38f; int bidx = 0;
    for (int k = 0; k < NCODE; ++k) {
        float dist = (xn + cnl[g][k]) - 2.0f * dotc(xr, cbg + (size_t)k * DG);
        if (dist < bestv) { bestv = dist; bidx = k; }
    }
    const float4* q4 = reinterpret_cast<const float4*>(cbg + (size_t)bidx * DG);
    float4* o4 = reinterpret_cast<float4*>(out + (size_t)token * DMODEL + g * DG);
    #pragma unroll
    for (int j = 0; j < 16; ++j) o4[j] = q4[j];
}

extern "C" void kernel_launch(void* const* d_in, const int* in_sizes, int n_in,
                              void* d_out, int out_size, void* d_ws, size_t ws_size,
                              hipStream_t stream) {
    const float* x  = (const float*)d_in[0];
    const float* cb = (const float*)d_in[1];
    float* out = (float*)d_out;

    const size_t wb_bytes = (size_t)NGRP * NCODE * DG * sizeof(__bf16); // 1 MB
    const size_t cn_bytes = (size_t)NGRP * NCODE * sizeof(float);       // 32 KB
    if (ws_size < wb_bytes + cn_bytes) {
        vq_fp32_kernel<<<256, 512, 0, stream>>>(x, cb, out);
        return;
    }
    __bf16* wb  = (__bf16*)d_ws;
    float*  wcn = (float*)((char*)d_ws + wb_bytes);

    prep_frags<<<256, 256, 0, stream>>>(cb, wb);
    prep_cnorm<<<32, 256, 0, stream>>>(cb, wcn);
    vq_mfma_kernel<<<1024, 256, 0, stream>>>(x, cb, wb, wcn, out);
}